// Round 1
// baseline (80.956 us; speedup 1.0000x reference)
//
#include <hip/hip_runtime.h>

// SKANLinear: y[b,o] = sum_{i=0}^{IN} weight[o,i] * sin(w[o,i] * x_ext[b,i])
// x_ext[b,IN] = 1.0 (bias column).
// B=2048, IN=256, OUT=256. f32 in, f32 out.
//
// Compute-bound on v_sin_f32 (quarter-rate): ~10.3 us floor.
// Wave layout: lane = 16*og + iq. og selects one of 4 o-rows per wave,
// iq selects a 4-float i-quad. Weight loads: 4 contiguous 256B segments per
// wave (coalesced). x loads: one 256B segment, broadcast across og groups.
// Each lane accumulates BTILE batches over its i-slice; shfl_xor(1,2,4,8)
// reduces across the 16 iq lanes. No LDS.

#define IN_DIM 256
#define OUT_DIM 256
#define LDW 257      // weight row stride = IN+1
#define BTILE 8      // batches per block
#define OTILE 16     // o-rows per block (4 waves x 4 og)

__global__ __launch_bounds__(256, 4)
void skan_kernel(const float* __restrict__ x,      // [B][256]
                 const float* __restrict__ weight, // [256][257]
                 const float* __restrict__ wfreq,  // [256][257]
                 float* __restrict__ y)            // [B][256]
{
    const int tid  = threadIdx.x;
    const int lane = tid & 63;
    const int wave = tid >> 6;
    const int iq   = lane & 15;              // i-quad index within 16
    const int og   = wave * 4 + (lane >> 4); // 0..15: o within block

    const int obase = (blockIdx.x & 15) * OTILE;
    const int b0    = (blockIdx.x >> 4) * BTILE;
    const int o     = obase + og;

    const float* wr = wfreq  + o * LDW;
    const float* gr = weight + o * LDW;

    float acc[BTILE];
#pragma unroll
    for (int b = 0; b < BTILE; ++b) acc[b] = 0.f;

#pragma unroll
    for (int c = 0; c < 4; ++c) {
        const int i = c * 64 + iq * 4;
        // rows are only 4B-aligned (stride 257): scalar dword loads,
        // coalesced across the 16-lane iq group.
        const float w0 = wr[i], w1 = wr[i + 1], w2 = wr[i + 2], w3 = wr[i + 3];
        const float g0 = gr[i], g1 = gr[i + 1], g2 = gr[i + 2], g3 = gr[i + 3];
#pragma unroll
        for (int b = 0; b < BTILE; ++b) {
            // x rows are 1024B-aligned: vector load OK
            const float4 xv = *(const float4*)(x + (b0 + b) * IN_DIM + i);
            float a = acc[b];
            a = fmaf(g0, __sinf(w0 * xv.x), a);
            a = fmaf(g1, __sinf(w1 * xv.y), a);
            a = fmaf(g2, __sinf(w2 * xv.z), a);
            a = fmaf(g3, __sinf(w3 * xv.w), a);
            acc[b] = a;
        }
    }

    // bias column: i = IN, x_ext = 1.0 -> same term for every b.
    // Add it on exactly one iq lane so the reduction counts it once.
    const float bias = gr[IN_DIM] * __sinf(wr[IN_DIM]);
    const float sel  = (iq == 0) ? bias : 0.f;
#pragma unroll
    for (int b = 0; b < BTILE; ++b) acc[b] += sel;

    // reduce across the 16 iq lanes (contiguous lanes within each og group)
#pragma unroll
    for (int b = 0; b < BTILE; ++b) {
        float v = acc[b];
        v += __shfl_xor(v, 1);
        v += __shfl_xor(v, 2);
        v += __shfl_xor(v, 4);
        v += __shfl_xor(v, 8);
        acc[b] = v;
    }

    if (iq == 0) {
#pragma unroll
        for (int b = 0; b < BTILE; ++b) {
            y[(b0 + b) * OUT_DIM + o] = acc[b];
        }
    }
}

extern "C" void kernel_launch(void* const* d_in, const int* in_sizes, int n_in,
                              void* d_out, int out_size, void* d_ws, size_t ws_size,
                              hipStream_t stream) {
    const float* x      = (const float*)d_in[0];
    const float* weight = (const float*)d_in[1];
    const float* wfreq  = (const float*)d_in[2];
    float* y            = (float*)d_out;

    const int B = in_sizes[0] / IN_DIM;          // 2048
    const int grid = (OUT_DIM / OTILE) * (B / BTILE); // 16 * 256 = 4096

    skan_kernel<<<grid, 256, 0, stream>>>(x, weight, wfreq, y);
}

// Round 2
// 78.903 us; speedup vs baseline: 1.0260x; 1.0260x over previous
//
#include <hip/hip_runtime.h>

// SKANLinear: y[b,o] = sum_{i=0}^{IN} weight[o,i] * sin(w[o,i] * x_ext[b,i])
// x_ext[b,IN] = 1.0 (bias column). B=2048, IN=256, OUT=256. f32.
//
// R1 fix: __sinf maps to precise __ocml_sin_f32 (~40 instrs) without
// -fgpu-approx-transcendentals -> 81 us. Force the HW instruction with
// __builtin_amdgcn_sinf (v_sin_f32, quarter-rate, input in REVOLUTIONS).
// Fold 1/(2pi) into w at load time: per element = v_mul + v_sin + v_fma
// = 12 cyc/wave-group -> ~10.3 us floor.
//
// Wave layout: lane = 16*og + iq. og picks one of 4 o-rows per wave,
// iq picks a 4-float i-quad. Weight loads coalesce into 4x256B segments
// per wave; x loads are one 256B segment broadcast across og groups.
// shfl_xor(1,2,4,8) reduces the 16 iq lanes. No LDS.

#define IN_DIM 256
#define OUT_DIM 256
#define LDW 257      // weight row stride = IN+1
#define BTILE 8      // batches per block
#define OTILE 16     // o-rows per block (4 waves x 4 og)

#define INV_2PI 0.15915494309189535f

__global__ __launch_bounds__(256, 4)
void skan_kernel(const float* __restrict__ x,      // [B][256]
                 const float* __restrict__ weight, // [256][257]
                 const float* __restrict__ wfreq,  // [256][257]
                 float* __restrict__ y)            // [B][256]
{
    const int tid  = threadIdx.x;
    const int lane = tid & 63;
    const int wave = tid >> 6;
    const int iq   = lane & 15;              // i-quad index within 16
    const int og   = wave * 4 + (lane >> 4); // 0..15: o within block

    const int obase = (blockIdx.x & 15) * OTILE;
    const int b0    = (blockIdx.x >> 4) * BTILE;
    const int o     = obase + og;

    const float* wr = wfreq  + o * LDW;
    const float* gr = weight + o * LDW;

    float acc[BTILE];
#pragma unroll
    for (int b = 0; b < BTILE; ++b) acc[b] = 0.f;

#pragma unroll
    for (int c = 0; c < 4; ++c) {
        const int i = c * 64 + iq * 4;
        // rows are only 4B-aligned (stride 257): scalar dword loads,
        // coalesced across the 16-lane iq group.
        // Pre-scale w by 1/(2pi): v_sin_f32 takes revolutions.
        const float w0 = wr[i]     * INV_2PI;
        const float w1 = wr[i + 1] * INV_2PI;
        const float w2 = wr[i + 2] * INV_2PI;
        const float w3 = wr[i + 3] * INV_2PI;
        const float g0 = gr[i], g1 = gr[i + 1], g2 = gr[i + 2], g3 = gr[i + 3];
#pragma unroll
        for (int b = 0; b < BTILE; ++b) {
            // x rows are 1024B-aligned: vector load OK
            const float4 xv = *(const float4*)(x + (b0 + b) * IN_DIM + i);
            float a = acc[b];
            a = fmaf(g0, __builtin_amdgcn_sinf(w0 * xv.x), a);
            a = fmaf(g1, __builtin_amdgcn_sinf(w1 * xv.y), a);
            a = fmaf(g2, __builtin_amdgcn_sinf(w2 * xv.z), a);
            a = fmaf(g3, __builtin_amdgcn_sinf(w3 * xv.w), a);
            acc[b] = a;
        }
    }

    // bias column: i = IN, x_ext = 1.0 -> same term for every b.
    // Add it on exactly one iq lane so the reduction counts it once.
    const float bias = gr[IN_DIM] * __builtin_amdgcn_sinf(wr[IN_DIM] * INV_2PI);
    const float sel  = (iq == 0) ? bias : 0.f;
#pragma unroll
    for (int b = 0; b < BTILE; ++b) acc[b] += sel;

    // reduce across the 16 iq lanes (contiguous lanes within each og group)
#pragma unroll
    for (int b = 0; b < BTILE; ++b) {
        float v = acc[b];
        v += __shfl_xor(v, 1);
        v += __shfl_xor(v, 2);
        v += __shfl_xor(v, 4);
        v += __shfl_xor(v, 8);
        acc[b] = v;
    }

    if (iq == 0) {
#pragma unroll
        for (int b = 0; b < BTILE; ++b) {
            y[(b0 + b) * OUT_DIM + o] = acc[b];
        }
    }
}

extern "C" void kernel_launch(void* const* d_in, const int* in_sizes, int n_in,
                              void* d_out, int out_size, void* d_ws, size_t ws_size,
                              hipStream_t stream) {
    const float* x      = (const float*)d_in[0];
    const float* weight = (const float*)d_in[1];
    const float* wfreq  = (const float*)d_in[2];
    float* y            = (float*)d_out;

    const int B = in_sizes[0] / IN_DIM;               // 2048
    const int grid = (OUT_DIM / OTILE) * (B / BTILE); // 16 * 256 = 4096

    skan_kernel<<<grid, 256, 0, stream>>>(x, weight, wfreq, y);
}